// Round 19
// baseline (1177.343 us; speedup 1.0000x reference)
//
#include <hip/hip_runtime.h>

// GRU recurrence (round 19).
// r18 verified: tile-major LDS killed conflicts (13.6M->946K), ROWS halving
// bought 256us (batch-proportional terms ~30% of step). Continue: ROWS=4,
// 256 blocks -> ALL CUs active; per-CU w_hh stream floor unchanged (6.1K
// cyc/step) but batch terms halve again. L2 aggregate/XCD = 12.6MB/step ~=
// per-CU floor, no thrash (weights shared + L2-resident, git nt-streamed).

typedef __attribute__((ext_vector_type(8))) short short8;
typedef __attribute__((ext_vector_type(4))) float f32x4;

constexpr int B_ = 1024, T_ = 128, I_ = 128, H_ = 256, OUT_ = 64;
constexpr int ROWS = 4;
constexpr int NBLK = B_ / ROWS;  // 256

#define DEVI __device__ __forceinline__

DEVI unsigned short f2b(float f) {
    unsigned u = __builtin_bit_cast(unsigned, f);
    u += 0x7fffu + ((u >> 16) & 1u);
    return (unsigned short)(u >> 16);
}
DEVI float b2f(unsigned short s) {
    unsigned u = ((unsigned)s) << 16;
    return __builtin_bit_cast(float, u);
}
DEVI unsigned cvtpk(float lo, float hi) {
    unsigned r;
    asm("v_cvt_pk_bf16_f32 %0, %1, %2" : "=v"(r) : "v"(lo), "v"(hi));
    return r;
}
DEVI float sigmoid2_(float x) {
    float e = __builtin_amdgcn_exp2f(-1.44269504f * x);
    return __builtin_amdgcn_rcpf(1.f + e);
}
DEVI float tanh2_(float x) {
    float e = __builtin_amdgcn_exp2f(2.88539009f * x);
    return (e - 1.f) * __builtin_amdgcn_rcpf(e + 1.f);
}

DEVI f32x4 ld4(const void* p) { return *reinterpret_cast<const f32x4*>(p); }
DEVI short8 ldg8(const unsigned short* p) {
    return __builtin_bit_cast(short8, *reinterpret_cast<const uint4*>(p));
}
DEVI short8 pack8(f32x4 lo, f32x4 hi) {
    union { unsigned u[4]; short8 v; } r;
    r.u[0] = cvtpk(lo[0], lo[1]); r.u[1] = cvtpk(lo[2], lo[3]);
    r.u[2] = cvtpk(hi[0], hi[1]); r.u[3] = cvtpk(hi[2], hi[3]);
    return r.v;
}
DEVI f32x4 mfma(short8 a, short8 b, f32x4 c) {
    return __builtin_amdgcn_mfma_f32_16x16x32_bf16(a, b, c, 0, 0, 0);
}
DEVI f32x4 ull2f4(unsigned long long raw) {
    f32x4 r;
#pragma unroll
    for (int e = 0; e < 4; ++e) r[e] = b2f((unsigned short)(raw >> (16 * e)));
    return r;
}
// tile-major offsets (elem units)
DEVI int hoff(int b, int c) {        // h/hn: b 0..3, c 0..255 -> [kt][kg][b][8]
    return (c >> 5) * 128 + ((c >> 3) & 3) * 32 + b * 8 + (c & 7);
}
DEVI int woff(int r, int c) {        // wst: r 0..255, c 0..255
    return ((r >> 4) * 8 + (c >> 5)) * 512 + ((c >> 3) & 3) * 128 + (r & 15) * 8 + (c & 7);
}
// legacy swizzle (fallback kernel only)
DEVI unsigned short* swz(unsigned short* base, int row, int col) {
    int byte = (row * 256 + col) * 2;
    byte ^= (row & 7) << 4;
    return (unsigned short*)((char*)base + byte);
}
DEVI const unsigned short* swzc(const unsigned short* base, int row, int col) {
    int byte = (row * 256 + col) * 2;
    byte ^= (row & 7) << 4;
    return (const unsigned short*)((const char*)base + byte);
}

// ---- weight pre-conversion: f32 -> bf16 ----
__global__ void cvt_w(const float* __restrict__ src, unsigned short* __restrict__ dst, int n) {
    int i = (blockIdx.x * blockDim.x + threadIdx.x) * 8;
    if (i >= n) return;
    f32x4 lo = ld4(src + i), hi = ld4(src + i + 4);
    union { unsigned short s[8]; uint4 v; } r;
#pragma unroll
    for (int e = 0; e < 4; ++e) { r.s[e] = f2b(lo[e]); r.s[4 + e] = f2b(hi[e]); }
    *reinterpret_cast<uint4*>(dst + i) = r.v;
}

// ---- gi precompute: git[((t*256 + b>>2)*4 + (b&3))*768 + gate], swapped D ----
__global__ __launch_bounds__(256) void gi_gemm(
    const float* __restrict__ a, const unsigned short* __restrict__ wih,
    unsigned short* __restrict__ git)
{
    const int tid = threadIdx.x;
    const int ww = tid >> 6;
    const int l = tid & 63;
    const int m = l & 15, kg = l >> 4;
    const int b0 = blockIdx.x * 64 + ww * 16;
    const int t = blockIdx.y;

    short8 xb[4];
    {
        const float* xr = a + (size_t)(b0 + m) * T_ * I_ + (size_t)t * I_ + kg * 8;
#pragma unroll
        for (int kt = 0; kt < 4; ++kt)
            xb[kt] = pack8(ld4(xr + kt * 32), ld4(xr + kt * 32 + 4));
    }
    const int b = b0 + m;
    unsigned short* gdst = git + (((size_t)t * 256 + (b >> 2)) * 4 + (b & 3)) * 768;
#pragma unroll 4
    for (int tl = 0; tl < 48; ++tl) {
        const int gr0 = tl * 16;
        short8 aw[4];
#pragma unroll
        for (int kt = 0; kt < 4; ++kt)
            aw[kt] = ldg8(wih + (size_t)(gr0 + m) * I_ + kt * 32 + kg * 8);
        f32x4 acc = {0.f, 0.f, 0.f, 0.f};
#pragma unroll
        for (int kt = 0; kt < 4; ++kt) acc = mfma(aw[kt], xb[kt], acc);
        const unsigned long long pk =
            (unsigned long long)cvtpk(acc[0], acc[1]) |
            ((unsigned long long)cvtpk(acc[2], acc[3]) << 32);
        __builtin_nontemporal_store(pk, reinterpret_cast<unsigned long long*>(
            gdst + gr0 + kg * 4));
    }
}

// ---- main kernel: 256 blocks x 1024 threads, ROWS=4, tile-major LDS ----
__global__ __launch_bounds__(1024, 4) void gru_fused4(
    const float* __restrict__ s0,             // [B][H] f32
    const unsigned short* __restrict__ git,   // [T][256][4][768] bf16
    const unsigned short* __restrict__ w_hh,  // [3H][H] bf16
    const unsigned short* __restrict__ w_rw,  // [OUT][H] bf16
    const unsigned short* __restrict__ w_st,  // [H][H] bf16
    float* __restrict__ out_r,                // [T][OUT] f32
    float* __restrict__ out_s)                // [B][T][H] f32
{
    __shared__ unsigned short wst_l[H_ * 256];  // 131072 B, tile-major
    __shared__ unsigned short h16[ROWS * 256];  // 2048 B, tile-major
    __shared__ unsigned short hn16[ROWS * 256]; // 2048 B   total 135168

    const int tid = threadIdx.x;
    const int w = tid >> 6;       // wave 0..15: gate/state rows w*16..+15
    const int l = tid & 63;
    const int m = l & 15;         // batch (D col); valid m<4, m>=4 mirrors
    const int kg = l >> 4;
    const int R0 = blockIdx.x * ROWS;
    const int gq = w * 16 + kg * 4;   // this lane's 4 D-rows (gate/state cols)

    // stage w_state into LDS, tile-major (65536 elems; 8 uint4 per thread)
#pragma unroll
    for (int i = 0; i < 8; ++i) {
        const int idx = (tid + i * 1024) * 8;
        *reinterpret_cast<uint4*>(&wst_l[woff(idx >> 8, idx & 255)]) =
            *reinterpret_cast<const uint4*>(w_st + idx);
    }
    // init h16 (1024 elems, 128 threads x 8)
    if (tid < 128) {
        const int b = tid >> 5, c0 = (tid & 31) * 8;
        const float* sp = &s0[(size_t)(R0 + b) * H_ + c0];
        *reinterpret_cast<uint4*>(&h16[hoff(b, c0)]) =
            __builtin_bit_cast(uint4, pack8(ld4(sp), ld4(sp + 4)));
    }
    // f32 carry: lane m<4 holds s[batch m][gq..gq+3]
    float hreg[4] = {0.f, 0.f, 0.f, 0.f};
    if (m < 4) {
        f32x4 h0 = ld4(&s0[(size_t)(R0 + m) * H_ + gq]);
#pragma unroll
        for (int v = 0; v < 4; ++v) hreg[v] = h0[v];
    }
    __syncthreads();

    const unsigned short* pwh = w_hh + (size_t)(w * 16 + m) * H_ + kg * 8;

    // git prefetch (t=0): 3 u64 (r,z,ni)
    const size_t gstep = (size_t)256 * 4 * 768;
    const unsigned short* gbase =
        git + ((size_t)blockIdx.x * 4 + (m & 3)) * 768;
    unsigned long long g0_, g1_, g2_;
    g0_ = __builtin_nontemporal_load(
        reinterpret_cast<const unsigned long long*>(gbase + gq));
    g1_ = __builtin_nontemporal_load(
        reinterpret_cast<const unsigned long long*>(gbase + gq + 256));
    g2_ = __builtin_nontemporal_load(
        reinterpret_cast<const unsigned long long*>(gbase + gq + 512));

    for (int t = 0; t < T_; ++t) {
        // ---- phase 1: gate GEMM, A = w_hh rows, B = h (tile-major LDS) ----
        f32x4 ar  = ull2f4(g0_);
        f32x4 az  = ull2f4(g1_);
        f32x4 ani = ull2f4(g2_);
        f32x4 anh = {0.f, 0.f, 0.f, 0.f};

        short8 ha[8];
#pragma unroll
        for (int kt = 0; kt < 8; ++kt)
            ha[kt] = ldg8(&h16[kt * 128 + kg * 32 + (m & 3) * 8]);
#pragma unroll
        for (int kt = 0; kt < 8; ++kt)
            ar  = mfma(ldg8(pwh + kt * 32),            ha[kt], ar);
#pragma unroll
        for (int kt = 0; kt < 8; ++kt)
            az  = mfma(ldg8(pwh + 256 * H_ + kt * 32), ha[kt], az);
#pragma unroll
        for (int kt = 0; kt < 8; ++kt)
            anh = mfma(ldg8(pwh + 512 * H_ + kt * 32), ha[kt], anh);

        // ---- gates -> h_new (lane m<4 writes 8B) ----
        if (m < 4) {
            float hv[4];
#pragma unroll
            for (int v = 0; v < 4; ++v) {
                const float rg = sigmoid2_(ar[v]);
                const float zg = sigmoid2_(az[v]);
                const float ng = tanh2_(ani[v] + rg * anh[v]);
                hv[v] = (1.f - zg) * ng + zg * hreg[v];
            }
            uint2 pk; pk.x = cvtpk(hv[0], hv[1]); pk.y = cvtpk(hv[2], hv[3]);
            *reinterpret_cast<uint2*>(&hn16[hoff(m, gq)]) = pk;
        }
        __syncthreads();                      // S1: hn16 ready

        // ---- prefetch git(t+1) ----
        {
            const int tn = (t + 1 < T_) ? t + 1 : t;
            const unsigned short* gt = gbase + (size_t)tn * gstep;
            g0_ = __builtin_nontemporal_load(
                reinterpret_cast<const unsigned long long*>(gt + gq));
            g1_ = __builtin_nontemporal_load(
                reinterpret_cast<const unsigned long long*>(gt + gq + 256));
            g2_ = __builtin_nontemporal_load(
                reinterpret_cast<const unsigned long long*>(gt + gq + 512));
        }

        // ---- phase 2: s = sig(hn @ w_state^T), A = wst (LDS), B = hn ----
        short8 na[8];
#pragma unroll
        for (int kt = 0; kt < 8; ++kt)
            na[kt] = ldg8(&hn16[kt * 128 + kg * 32 + (m & 3) * 8]);
        f32x4 sa = {0.f, 0.f, 0.f, 0.f};
#pragma unroll
        for (int kt = 0; kt < 8; ++kt)
            sa = mfma(ldg8(&wst_l[(w * 8 + kt) * 512 + kg * 128 + m * 8]),
                      na[kt], sa);
        if (m < 4) {
            float sv[4];
#pragma unroll
            for (int v = 0; v < 4; ++v) {
                sv[v] = sigmoid2_(sa[v]);
                hreg[v] = sv[v];
            }
            uint2 pk; pk.x = cvtpk(sv[0], sv[1]); pk.y = cvtpk(sv[2], sv[3]);
            *reinterpret_cast<uint2*>(&h16[hoff(m, gq)]) = pk;
            f32x4 o4 = {sv[0], sv[1], sv[2], sv[3]};
            __builtin_nontemporal_store(o4, reinterpret_cast<f32x4*>(
                &out_s[((size_t)(R0 + m) * T_ + t) * H_ + gq]));
        }
        if (blockIdx.x == 0 && w < 4) {       // r_t: A = w_rw rows w*16+m
            f32x4 accr = {0.f, 0.f, 0.f, 0.f};
            const unsigned short* p = w_rw + (size_t)(w * 16 + m) * H_ + kg * 8;
#pragma unroll
            for (int kt = 0; kt < 8; ++kt)
                accr = mfma(ldg8(p + kt * 32), na[kt], accr);
            if (m == 0) {                     // batch row 0 = D col 0
                f32x4 o4 = {sigmoid2_(accr[0]), sigmoid2_(accr[1]),
                            sigmoid2_(accr[2]), sigmoid2_(accr[3])};
                *reinterpret_cast<f32x4*>(&out_r[t * OUT_ + w * 16 + kg * 4]) = o4;
            }
        }
        __syncthreads();                      // S2: h16 ready for t+1
    }
}

// ---- fallback (ws too small): r17 streaming kernel, 64 blocks ----
__global__ __launch_bounds__(512, 1) void gru_fallback(
    const float* __restrict__ s0, const float* __restrict__ a,
    const unsigned short* __restrict__ w_ih, const unsigned short* __restrict__ w_hh,
    const unsigned short* __restrict__ w_rw, const unsigned short* __restrict__ w_st,
    float* __restrict__ out_r, float* __restrict__ out_s)
{
    __shared__ unsigned short wst_l[H_ * 256];
    __shared__ unsigned short h16a[16 * 256];
    __shared__ unsigned short hn16a[16 * 256];
    const int tid = threadIdx.x;
    const int w = tid >> 6, l = tid & 63, m = l & 15, kg = l >> 4;
    const int R0 = blockIdx.x * 16;
    const int g0 = (2 * w + 0) * 16 + m, g1 = (2 * w + 1) * 16 + m;
#pragma unroll
    for (int i = 0; i < 16; ++i) {
        const int idx = (tid + i * 512) * 8;
        *reinterpret_cast<uint4*>(swz(wst_l, idx >> 8, idx & 255)) =
            *reinterpret_cast<const uint4*>(w_st + idx);
    }
    {
        const int pr = tid >> 5, pc = (tid & 31) * 8;
        const float* sp = &s0[(size_t)(R0 + pr) * H_ + pc];
        *reinterpret_cast<uint4*>(swz(h16a, pr, pc)) =
            __builtin_bit_cast(uint4, pack8(ld4(sp), ld4(sp + 4)));
    }
    float hreg0[4], hreg1[4];
#pragma unroll
    for (int v = 0; v < 4; ++v) {
        hreg0[v] = s0[(size_t)(R0 + kg * 4 + v) * H_ + g0];
        hreg1[v] = s0[(size_t)(R0 + kg * 4 + v) * H_ + g1];
    }
    __syncthreads();
    for (int t = 0; t < T_; ++t) {
        short8 ha[8];
#pragma unroll
        for (int kt = 0; kt < 8; ++kt) ha[kt] = ldg8(swzc(h16a, m, kt * 32 + kg * 8));
        f32x4 ar0 = {0,0,0,0}, az0 = {0,0,0,0}, ani0 = {0,0,0,0};
        f32x4 ar1 = {0,0,0,0}, az1 = {0,0,0,0}, ani1 = {0,0,0,0};
        short8 xa[4];
        const float* xr = a + ((size_t)(R0 + m) * T_ + t) * I_ + kg * 8;
#pragma unroll
        for (int kt = 0; kt < 4; ++kt)
            xa[kt] = pack8(ld4(xr + kt * 32), ld4(xr + kt * 32 + 4));
        const unsigned short* p0 = w_ih + (size_t)g0 * I_ + kg * 8;
        const unsigned short* p1 = w_ih + (size_t)g1 * I_ + kg * 8;
#pragma unroll
        for (int kt = 0; kt < 4; ++kt) {
            ar0  = mfma(xa[kt], ldg8(p0 + kt * 32),            ar0);
            az0  = mfma(xa[kt], ldg8(p0 + 256 * I_ + kt * 32), az0);
            ani0 = mfma(xa[kt], ldg8(p0 + 512 * I_ + kt * 32), ani0);
            ar1  = mfma(xa[kt], ldg8(p1 + kt * 32),            ar1);
            az1  = mfma(xa[kt], ldg8(p1 + 256 * I_ + kt * 32), az1);
            ani1 = mfma(xa[kt], ldg8(p1 + 512 * I_ + kt * 32), ani1);
        }
        f32x4 anh0 = {0,0,0,0}, anh1 = {0,0,0,0};
        const unsigned short* q0 = w_hh + (size_t)g0 * H_ + kg * 8;
        const unsigned short* q1 = w_hh + (size_t)g1 * H_ + kg * 8;
#pragma unroll
        for (int kt = 0; kt < 8; ++kt) {
            ar0  = mfma(ha[kt], ldg8(q0 + kt * 32),            ar0);
            az0  = mfma(ha[kt], ldg8(q0 + 256 * H_ + kt * 32), az0);
            anh0 = mfma(ha[kt], ldg8(q0 + 512 * H_ + kt * 32), anh0);
            ar1  = mfma(ha[kt], ldg8(q1 + kt * 32),            ar1);
            az1  = mfma(ha[kt], ldg8(q1 + 256 * H_ + kt * 32), az1);
            anh1 = mfma(ha[kt], ldg8(q1 + 512 * H_ + kt * 32), anh1);
        }
#pragma unroll
        for (int v = 0; v < 4; ++v) {
            const int row = kg * 4 + v;
            float rg = sigmoid2_(ar0[v]), zg = sigmoid2_(az0[v]);
            float ng = tanh2_(ani0[v] + rg * anh0[v]);
            *swz(hn16a, row, g0) = f2b((1.f - zg) * ng + zg * hreg0[v]);
            rg = sigmoid2_(ar1[v]); zg = sigmoid2_(az1[v]);
            ng = tanh2_(ani1[v] + rg * anh1[v]);
            *swz(hn16a, row, g1) = f2b((1.f - zg) * ng + zg * hreg1[v]);
        }
        __syncthreads();
        short8 na[8];
#pragma unroll
        for (int kt = 0; kt < 8; ++kt) na[kt] = ldg8(swzc(hn16a, m, kt * 32 + kg * 8));
        f32x4 sa0 = {0,0,0,0}, sa1 = {0,0,0,0};
#pragma unroll
        for (int kt = 0; kt < 8; ++kt) {
            sa0 = mfma(na[kt], ldg8(swzc(wst_l, g0, kt * 32 + kg * 8)), sa0);
            sa1 = mfma(na[kt], ldg8(swzc(wst_l, g1, kt * 32 + kg * 8)), sa1);
        }
#pragma unroll
        for (int v = 0; v < 4; ++v) {
            const int row = kg * 4 + v;
            const float u0 = sigmoid2_(sa0[v]), u1 = sigmoid2_(sa1[v]);
            hreg0[v] = u0; hreg1[v] = u1;
            *swz(h16a, row, g0) = f2b(u0);
            *swz(h16a, row, g1) = f2b(u1);
            float* dst = &out_s[((size_t)(R0 + row) * T_ + t) * H_];
            dst[g0] = u0; dst[g1] = u1;
        }
        if (blockIdx.x == 0 && w < 4) {
            const int o = w * 16 + m;
            f32x4 accr = {0,0,0,0};
            const unsigned short* pw = w_rw + (size_t)o * H_ + kg * 8;
#pragma unroll
            for (int kt = 0; kt < 8; ++kt) accr = mfma(na[kt], ldg8(pw + kt * 32), accr);
            if (kg == 0) out_r[t * OUT_ + o] = sigmoid2_(accr[0]);
        }
        __syncthreads();
    }
}

extern "C" void kernel_launch(void* const* d_in, const int* in_sizes, int n_in,
                              void* d_out, int out_size, void* d_ws, size_t ws_size,
                              hipStream_t stream) {
    const float* s0  = (const float*)d_in[0];
    const float* a   = (const float*)d_in[1];
    const float* wih = (const float*)d_in[2];
    const float* whh = (const float*)d_in[3];
    const float* wrw = (const float*)d_in[4];
    const float* wst = (const float*)d_in[5];

    const size_t git_e  = (size_t)T_ * 256 * 4 * 768;     // 100,663,296 u16
    const size_t wtot_e = 98304 + 196608 + 16384 + 65536; // 376,832 u16
    const bool pregi = ws_size >= (git_e + wtot_e) * 2;

    unsigned short* ws16  = (unsigned short*)d_ws;
    unsigned short* git   = ws16;
    unsigned short* wih16 = ws16 + (pregi ? git_e : 0);
    unsigned short* whh16 = wih16 + 98304;
    unsigned short* wrw16 = whh16 + 196608;
    unsigned short* wst16 = wrw16 + 16384;

    cvt_w<<<98304  / (256 * 8), 256, 0, stream>>>(wih, wih16, 98304);
    cvt_w<<<196608 / (256 * 8), 256, 0, stream>>>(whh, whh16, 196608);
    cvt_w<<<16384  / (256 * 8), 256, 0, stream>>>(wrw, wrw16, 16384);
    cvt_w<<<65536  / (256 * 8), 256, 0, stream>>>(wst, wst16, 65536);

    float* out = (float*)d_out;
    if (pregi) {
        gi_gemm<<<dim3(16, T_), 256, 0, stream>>>(a, wih16, git);
        gru_fused4<<<NBLK, 1024, 0, stream>>>(s0, git, whh16, wrw16, wst16,
                                              out, out + (size_t)T_ * OUT_);
    } else {
        gru_fallback<<<64, 512, 0, stream>>>(s0, a, wih16, whh16, wrw16, wst16,
                                             out, out + (size_t)T_ * OUT_);
    }
}

// Round 20
// 1034.705 us; speedup vs baseline: 1.1379x; 1.1379x over previous
//
#include <hip/hip_runtime.h>

// GRU recurrence (round 20 = revert to round-18 champion).
// r19 (ROWS=4, 256 blocks) falsified: per-XCD weight demand exceeded L2 ->
// HBM re-fetch (FETCH 110MB->1.28GB), dur 854->1020us. r18 is the measured
// optimum of this structure: 128 blocks x ROWS=8, tile-major conflict-free
// LDS, w_state LDS-resident, gi-precompute + nt double-buffered git,
// swapped-operand MFMAs, exp2 activations, packed 8B/16B stores.

typedef __attribute__((ext_vector_type(8))) short short8;
typedef __attribute__((ext_vector_type(4))) float f32x4;

constexpr int B_ = 1024, T_ = 128, I_ = 128, H_ = 256, OUT_ = 64;
constexpr int ROWS = 8;
constexpr int NBLK = B_ / ROWS;  // 128

#define DEVI __device__ __forceinline__

DEVI unsigned short f2b(float f) {
    unsigned u = __builtin_bit_cast(unsigned, f);
    u += 0x7fffu + ((u >> 16) & 1u);
    return (unsigned short)(u >> 16);
}
DEVI float b2f(unsigned short s) {
    unsigned u = ((unsigned)s) << 16;
    return __builtin_bit_cast(float, u);
}
DEVI unsigned cvtpk(float lo, float hi) {
    unsigned r;
    asm("v_cvt_pk_bf16_f32 %0, %1, %2" : "=v"(r) : "v"(lo), "v"(hi));
    return r;
}
DEVI float sigmoid2_(float x) {
    float e = __builtin_amdgcn_exp2f(-1.44269504f * x);
    return __builtin_amdgcn_rcpf(1.f + e);
}
DEVI float tanh2_(float x) {
    float e = __builtin_amdgcn_exp2f(2.88539009f * x);
    return (e - 1.f) * __builtin_amdgcn_rcpf(e + 1.f);
}

DEVI f32x4 ld4(const void* p) { return *reinterpret_cast<const f32x4*>(p); }
DEVI short8 ldg8(const unsigned short* p) {
    return __builtin_bit_cast(short8, *reinterpret_cast<const uint4*>(p));
}
DEVI short8 pack8(f32x4 lo, f32x4 hi) {
    union { unsigned u[4]; short8 v; } r;
    r.u[0] = cvtpk(lo[0], lo[1]); r.u[1] = cvtpk(lo[2], lo[3]);
    r.u[2] = cvtpk(hi[0], hi[1]); r.u[3] = cvtpk(hi[2], hi[3]);
    return r.v;
}
DEVI f32x4 mfma(short8 a, short8 b, f32x4 c) {
    return __builtin_amdgcn_mfma_f32_16x16x32_bf16(a, b, c, 0, 0, 0);
}
DEVI f32x4 ull2f4(unsigned long long raw) {
    f32x4 r;
#pragma unroll
    for (int e = 0; e < 4; ++e) r[e] = b2f((unsigned short)(raw >> (16 * e)));
    return r;
}
// tile-major offsets (elem units)
DEVI int hoff(int b, int c) {        // h/hn: b 0..7, c 0..255
    return (c >> 5) * 256 + ((c >> 3) & 3) * 64 + b * 8 + (c & 7);
}
DEVI int woff(int r, int c) {        // wst: r 0..255, c 0..255
    return ((r >> 4) * 8 + (c >> 5)) * 512 + ((c >> 3) & 3) * 128 + (r & 15) * 8 + (c & 7);
}
// legacy swizzle (fallback kernel only)
DEVI unsigned short* swz(unsigned short* base, int row, int col) {
    int byte = (row * 256 + col) * 2;
    byte ^= (row & 7) << 4;
    return (unsigned short*)((char*)base + byte);
}
DEVI const unsigned short* swzc(const unsigned short* base, int row, int col) {
    int byte = (row * 256 + col) * 2;
    byte ^= (row & 7) << 4;
    return (const unsigned short*)((const char*)base + byte);
}

// ---- weight pre-conversion: f32 -> bf16 ----
__global__ void cvt_w(const float* __restrict__ src, unsigned short* __restrict__ dst, int n) {
    int i = (blockIdx.x * blockDim.x + threadIdx.x) * 8;
    if (i >= n) return;
    f32x4 lo = ld4(src + i), hi = ld4(src + i + 4);
    union { unsigned short s[8]; uint4 v; } r;
#pragma unroll
    for (int e = 0; e < 4; ++e) { r.s[e] = f2b(lo[e]); r.s[4 + e] = f2b(hi[e]); }
    *reinterpret_cast<uint4*>(dst + i) = r.v;
}

// ---- gi precompute: git[((t*128 + rb)*8 + b&7)*768 + gate], swapped D ----
__global__ __launch_bounds__(256) void gi_gemm(
    const float* __restrict__ a, const unsigned short* __restrict__ wih,
    unsigned short* __restrict__ git)
{
    const int tid = threadIdx.x;
    const int ww = tid >> 6;
    const int l = tid & 63;
    const int m = l & 15, kg = l >> 4;
    const int b0 = blockIdx.x * 64 + ww * 16;
    const int t = blockIdx.y;

    short8 xb[4];
    {
        const float* xr = a + (size_t)(b0 + m) * T_ * I_ + (size_t)t * I_ + kg * 8;
#pragma unroll
        for (int kt = 0; kt < 4; ++kt)
            xb[kt] = pack8(ld4(xr + kt * 32), ld4(xr + kt * 32 + 4));
    }
    const int b = b0 + m;
    unsigned short* gdst = git + (((size_t)t * 128 + (b >> 3)) * 8 + (b & 7)) * 768;
#pragma unroll 4
    for (int tl = 0; tl < 48; ++tl) {
        const int gr0 = tl * 16;
        short8 aw[4];
#pragma unroll
        for (int kt = 0; kt < 4; ++kt)
            aw[kt] = ldg8(wih + (size_t)(gr0 + m) * I_ + kt * 32 + kg * 8);
        f32x4 acc = {0.f, 0.f, 0.f, 0.f};
#pragma unroll
        for (int kt = 0; kt < 4; ++kt) acc = mfma(aw[kt], xb[kt], acc);
        const unsigned long long pk =
            (unsigned long long)cvtpk(acc[0], acc[1]) |
            ((unsigned long long)cvtpk(acc[2], acc[3]) << 32);
        __builtin_nontemporal_store(pk, reinterpret_cast<unsigned long long*>(
            gdst + gr0 + kg * 4));
    }
}

// ---- main kernel: 128 blocks x 1024 threads, ROWS=8, tile-major LDS ----
__global__ __launch_bounds__(1024, 4) void gru_fused8(
    const float* __restrict__ s0,             // [B][H] f32
    const unsigned short* __restrict__ git,   // [T][128][8][768] bf16
    const unsigned short* __restrict__ w_hh,  // [3H][H] bf16
    const unsigned short* __restrict__ w_rw,  // [OUT][H] bf16
    const unsigned short* __restrict__ w_st,  // [H][H] bf16
    float* __restrict__ out_r,                // [T][OUT] f32
    float* __restrict__ out_s)                // [B][T][H] f32
{
    __shared__ unsigned short wst_l[H_ * 256];  // 131072 B, tile-major
    __shared__ unsigned short h16[ROWS * 256];  // 4096 B, tile-major
    __shared__ unsigned short hn16[ROWS * 256]; // 4096 B   total 139264

    const int tid = threadIdx.x;
    const int w = tid >> 6;       // wave 0..15: gate/state rows w*16..+15
    const int l = tid & 63;
    const int m = l & 15;         // batch (D col); valid m<8, m>=8 mirrors
    const int kg = l >> 4;
    const int R0 = blockIdx.x * ROWS;
    const int gq = w * 16 + kg * 4;   // this lane's 4 D-rows (gate/state cols)

    // stage w_state into LDS, tile-major (65536 elems; 8 uint4 per thread)
#pragma unroll
    for (int i = 0; i < 8; ++i) {
        const int idx = (tid + i * 1024) * 8;
        *reinterpret_cast<uint4*>(&wst_l[woff(idx >> 8, idx & 255)]) =
            *reinterpret_cast<const uint4*>(w_st + idx);
    }
    // init h16 (2048 elems, 256 threads x 8)
    if (tid < 256) {
        const int b = tid >> 5, c0 = (tid & 31) * 8;
        const float* sp = &s0[(size_t)(R0 + b) * H_ + c0];
        *reinterpret_cast<uint4*>(&h16[hoff(b, c0)]) =
            __builtin_bit_cast(uint4, pack8(ld4(sp), ld4(sp + 4)));
    }
    // f32 carry: lane m<8 holds s[batch m][gq..gq+3]
    float hreg[4] = {0.f, 0.f, 0.f, 0.f};
    if (m < 8) {
        f32x4 h0 = ld4(&s0[(size_t)(R0 + m) * H_ + gq]);
#pragma unroll
        for (int v = 0; v < 4; ++v) hreg[v] = h0[v];
    }
    __syncthreads();

    const unsigned short* pwh = w_hh + (size_t)(w * 16 + m) * H_ + kg * 8;

    // git prefetch (t=0): 3 u64 (r,z,ni) for lane m<8
    const size_t gstep = (size_t)128 * 8 * 768;
    const unsigned short* gbase =
        git + ((size_t)blockIdx.x * 8 + (m & 7)) * 768;
    unsigned long long g0_ = 0, g1_ = 0, g2_ = 0;
    if (m < 8) {
        g0_ = __builtin_nontemporal_load(
            reinterpret_cast<const unsigned long long*>(gbase + gq));
        g1_ = __builtin_nontemporal_load(
            reinterpret_cast<const unsigned long long*>(gbase + gq + 256));
        g2_ = __builtin_nontemporal_load(
            reinterpret_cast<const unsigned long long*>(gbase + gq + 512));
    }

    for (int t = 0; t < T_; ++t) {
        // ---- phase 1: gate GEMM, A = w_hh rows, B = h (tile-major LDS) ----
        f32x4 ar  = ull2f4(g0_);
        f32x4 az  = ull2f4(g1_);
        f32x4 ani = ull2f4(g2_);
        f32x4 anh = {0.f, 0.f, 0.f, 0.f};

        short8 ha[8];
#pragma unroll
        for (int kt = 0; kt < 8; ++kt)
            ha[kt] = ldg8(&h16[kt * 256 + kg * 64 + (m & 7) * 8]);
#pragma unroll
        for (int kt = 0; kt < 8; ++kt)
            ar  = mfma(ldg8(pwh + kt * 32),            ha[kt], ar);
#pragma unroll
        for (int kt = 0; kt < 8; ++kt)
            az  = mfma(ldg8(pwh + 256 * H_ + kt * 32), ha[kt], az);
#pragma unroll
        for (int kt = 0; kt < 8; ++kt)
            anh = mfma(ldg8(pwh + 512 * H_ + kt * 32), ha[kt], anh);

        // ---- gates -> h_new (lane m<8 writes 8B) ----
        if (m < 8) {
            float hv[4];
#pragma unroll
            for (int v = 0; v < 4; ++v) {
                const float rg = sigmoid2_(ar[v]);
                const float zg = sigmoid2_(az[v]);
                const float ng = tanh2_(ani[v] + rg * anh[v]);
                hv[v] = (1.f - zg) * ng + zg * hreg[v];
            }
            uint2 pk; pk.x = cvtpk(hv[0], hv[1]); pk.y = cvtpk(hv[2], hv[3]);
            *reinterpret_cast<uint2*>(&hn16[hoff(m, gq)]) = pk;
        }
        __syncthreads();                      // S1: hn16 ready

        // ---- prefetch git(t+1) ----
        if (m < 8) {
            const int tn = (t + 1 < T_) ? t + 1 : t;
            const unsigned short* gt = gbase + (size_t)tn * gstep;
            g0_ = __builtin_nontemporal_load(
                reinterpret_cast<const unsigned long long*>(gt + gq));
            g1_ = __builtin_nontemporal_load(
                reinterpret_cast<const unsigned long long*>(gt + gq + 256));
            g2_ = __builtin_nontemporal_load(
                reinterpret_cast<const unsigned long long*>(gt + gq + 512));
        }

        // ---- phase 2: s = sig(hn @ w_state^T), A = wst (LDS), B = hn ----
        short8 na[8];
#pragma unroll
        for (int kt = 0; kt < 8; ++kt)
            na[kt] = ldg8(&hn16[kt * 256 + kg * 64 + (m & 7) * 8]);
        f32x4 sa = {0.f, 0.f, 0.f, 0.f};
#pragma unroll
        for (int kt = 0; kt < 8; ++kt)
            sa = mfma(ldg8(&wst_l[(w * 8 + kt) * 512 + kg * 128 + m * 8]),
                      na[kt], sa);
        if (m < 8) {
            float sv[4];
#pragma unroll
            for (int v = 0; v < 4; ++v) {
                sv[v] = sigmoid2_(sa[v]);
                hreg[v] = sv[v];
            }
            uint2 pk; pk.x = cvtpk(sv[0], sv[1]); pk.y = cvtpk(sv[2], sv[3]);
            *reinterpret_cast<uint2*>(&h16[hoff(m, gq)]) = pk;
            f32x4 o4 = {sv[0], sv[1], sv[2], sv[3]};
            __builtin_nontemporal_store(o4, reinterpret_cast<f32x4*>(
                &out_s[((size_t)(R0 + m) * T_ + t) * H_ + gq]));
        }
        if (blockIdx.x == 0 && w < 4) {       // r_t: A = w_rw rows w*16+m
            f32x4 accr = {0.f, 0.f, 0.f, 0.f};
            const unsigned short* p = w_rw + (size_t)(w * 16 + m) * H_ + kg * 8;
#pragma unroll
            for (int kt = 0; kt < 8; ++kt)
                accr = mfma(ldg8(p + kt * 32), na[kt], accr);
            if (m == 0) {                     // batch row 0 = D col 0
                f32x4 o4 = {sigmoid2_(accr[0]), sigmoid2_(accr[1]),
                            sigmoid2_(accr[2]), sigmoid2_(accr[3])};
                *reinterpret_cast<f32x4*>(&out_r[t * OUT_ + w * 16 + kg * 4]) = o4;
            }
        }
        __syncthreads();                      // S2: h16 ready for t+1
    }
}

// ---- fallback (ws too small): streaming kernel, 64 blocks ----
__global__ __launch_bounds__(512, 1) void gru_fallback(
    const float* __restrict__ s0, const float* __restrict__ a,
    const unsigned short* __restrict__ w_ih, const unsigned short* __restrict__ w_hh,
    const unsigned short* __restrict__ w_rw, const unsigned short* __restrict__ w_st,
    float* __restrict__ out_r, float* __restrict__ out_s)
{
    __shared__ unsigned short wst_l[H_ * 256];
    __shared__ unsigned short h16a[16 * 256];
    __shared__ unsigned short hn16a[16 * 256];
    const int tid = threadIdx.x;
    const int w = tid >> 6, l = tid & 63, m = l & 15, kg = l >> 4;
    const int R0 = blockIdx.x * 16;
    const int g0 = (2 * w + 0) * 16 + m, g1 = (2 * w + 1) * 16 + m;
#pragma unroll
    for (int i = 0; i < 16; ++i) {
        const int idx = (tid + i * 512) * 8;
        *reinterpret_cast<uint4*>(swz(wst_l, idx >> 8, idx & 255)) =
            *reinterpret_cast<const uint4*>(w_st + idx);
    }
    {
        const int pr = tid >> 5, pc = (tid & 31) * 8;
        const float* sp = &s0[(size_t)(R0 + pr) * H_ + pc];
        *reinterpret_cast<uint4*>(swz(h16a, pr, pc)) =
            __builtin_bit_cast(uint4, pack8(ld4(sp), ld4(sp + 4)));
    }
    float hreg0[4], hreg1[4];
#pragma unroll
    for (int v = 0; v < 4; ++v) {
        hreg0[v] = s0[(size_t)(R0 + kg * 4 + v) * H_ + g0];
        hreg1[v] = s0[(size_t)(R0 + kg * 4 + v) * H_ + g1];
    }
    __syncthreads();
    for (int t = 0; t < T_; ++t) {
        short8 ha[8];
#pragma unroll
        for (int kt = 0; kt < 8; ++kt) ha[kt] = ldg8(swzc(h16a, m, kt * 32 + kg * 8));
        f32x4 ar0 = {0,0,0,0}, az0 = {0,0,0,0}, ani0 = {0,0,0,0};
        f32x4 ar1 = {0,0,0,0}, az1 = {0,0,0,0}, ani1 = {0,0,0,0};
        short8 xa[4];
        const float* xr = a + ((size_t)(R0 + m) * T_ + t) * I_ + kg * 8;
#pragma unroll
        for (int kt = 0; kt < 4; ++kt)
            xa[kt] = pack8(ld4(xr + kt * 32), ld4(xr + kt * 32 + 4));
        const unsigned short* p0 = w_ih + (size_t)g0 * I_ + kg * 8;
        const unsigned short* p1 = w_ih + (size_t)g1 * I_ + kg * 8;
#pragma unroll
        for (int kt = 0; kt < 4; ++kt) {
            ar0  = mfma(xa[kt], ldg8(p0 + kt * 32),            ar0);
            az0  = mfma(xa[kt], ldg8(p0 + 256 * I_ + kt * 32), az0);
            ani0 = mfma(xa[kt], ldg8(p0 + 512 * I_ + kt * 32), ani0);
            ar1  = mfma(xa[kt], ldg8(p1 + kt * 32),            ar1);
            az1  = mfma(xa[kt], ldg8(p1 + 256 * I_ + kt * 32), az1);
            ani1 = mfma(xa[kt], ldg8(p1 + 512 * I_ + kt * 32), ani1);
        }
        f32x4 anh0 = {0,0,0,0}, anh1 = {0,0,0,0};
        const unsigned short* q0 = w_hh + (size_t)g0 * H_ + kg * 8;
        const unsigned short* q1 = w_hh + (size_t)g1 * H_ + kg * 8;
#pragma unroll
        for (int kt = 0; kt < 8; ++kt) {
            ar0  = mfma(ha[kt], ldg8(q0 + kt * 32),            ar0);
            az0  = mfma(ha[kt], ldg8(q0 + 256 * H_ + kt * 32), az0);
            anh0 = mfma(ha[kt], ldg8(q0 + 512 * H_ + kt * 32), anh0);
            ar1  = mfma(ha[kt], ldg8(q1 + kt * 32),            ar1);
            az1  = mfma(ha[kt], ldg8(q1 + 256 * H_ + kt * 32), az1);
            anh1 = mfma(ha[kt], ldg8(q1 + 512 * H_ + kt * 32), anh1);
        }
#pragma unroll
        for (int v = 0; v < 4; ++v) {
            const int row = kg * 4 + v;
            float rg = sigmoid2_(ar0[v]), zg = sigmoid2_(az0[v]);
            float ng = tanh2_(ani0[v] + rg * anh0[v]);
            *swz(hn16a, row, g0) = f2b((1.f - zg) * ng + zg * hreg0[v]);
            rg = sigmoid2_(ar1[v]); zg = sigmoid2_(az1[v]);
            ng = tanh2_(ani1[v] + rg * anh1[v]);
            *swz(hn16a, row, g1) = f2b((1.f - zg) * ng + zg * hreg1[v]);
        }
        __syncthreads();
        short8 na[8];
#pragma unroll
        for (int kt = 0; kt < 8; ++kt) na[kt] = ldg8(swzc(hn16a, m, kt * 32 + kg * 8));
        f32x4 sa0 = {0,0,0,0}, sa1 = {0,0,0,0};
#pragma unroll
        for (int kt = 0; kt < 8; ++kt) {
            sa0 = mfma(na[kt], ldg8(swzc(wst_l, g0, kt * 32 + kg * 8)), sa0);
            sa1 = mfma(na[kt], ldg8(swzc(wst_l, g1, kt * 32 + kg * 8)), sa1);
        }
#pragma unroll
        for (int v = 0; v < 4; ++v) {
            const int row = kg * 4 + v;
            const float u0 = sigmoid2_(sa0[v]), u1 = sigmoid2_(sa1[v]);
            hreg0[v] = u0; hreg1[v] = u1;
            *swz(h16a, row, g0) = f2b(u0);
            *swz(h16a, row, g1) = f2b(u1);
            float* dst = &out_s[((size_t)(R0 + row) * T_ + t) * H_];
            dst[g0] = u0; dst[g1] = u1;
        }
        if (blockIdx.x == 0 && w < 4) {
            const int o = w * 16 + m;
            f32x4 accr = {0,0,0,0};
            const unsigned short* pw = w_rw + (size_t)o * H_ + kg * 8;
#pragma unroll
            for (int kt = 0; kt < 8; ++kt) accr = mfma(na[kt], ldg8(pw + kt * 32), accr);
            if (kg == 0) out_r[t * OUT_ + o] = sigmoid2_(accr[0]);
        }
        __syncthreads();
    }
}

extern "C" void kernel_launch(void* const* d_in, const int* in_sizes, int n_in,
                              void* d_out, int out_size, void* d_ws, size_t ws_size,
                              hipStream_t stream) {
    const float* s0  = (const float*)d_in[0];
    const float* a   = (const float*)d_in[1];
    const float* wih = (const float*)d_in[2];
    const float* whh = (const float*)d_in[3];
    const float* wrw = (const float*)d_in[4];
    const float* wst = (const float*)d_in[5];

    const size_t git_e  = (size_t)T_ * 128 * 8 * 768;     // 100,663,296 u16
    const size_t wtot_e = 98304 + 196608 + 16384 + 65536; // 376,832 u16
    const bool pregi = ws_size >= (git_e + wtot_e) * 2;

    unsigned short* ws16  = (unsigned short*)d_ws;
    unsigned short* git   = ws16;
    unsigned short* wih16 = ws16 + (pregi ? git_e : 0);
    unsigned short* whh16 = wih16 + 98304;
    unsigned short* wrw16 = whh16 + 196608;
    unsigned short* wst16 = wrw16 + 16384;

    cvt_w<<<98304  / (256 * 8), 256, 0, stream>>>(wih, wih16, 98304);
    cvt_w<<<196608 / (256 * 8), 256, 0, stream>>>(whh, whh16, 196608);
    cvt_w<<<16384  / (256 * 8), 256, 0, stream>>>(wrw, wrw16, 16384);
    cvt_w<<<65536  / (256 * 8), 256, 0, stream>>>(wst, wst16, 65536);

    float* out = (float*)d_out;
    if (pregi) {
        gi_gemm<<<dim3(16, T_), 256, 0, stream>>>(a, wih16, git);
        gru_fused8<<<NBLK, 1024, 0, stream>>>(s0, git, whh16, wrw16, wst16,
                                              out, out + (size_t)T_ * OUT_);
    } else {
        gru_fallback<<<64, 512, 0, stream>>>(s0, a, wih16, whh16, wrw16, wst16,
                                             out, out + (size_t)T_ * OUT_);
    }
}